// Round 5
// baseline (685.153 us; speedup 1.0000x reference)
//
#include <hip/hip_runtime.h>
#include <hip/hip_bf16.h>

#define N_PKT 131072
#define KD 128
#define DM 256
#define HDIM 256
#define NCOMP 1024
#define ADIM 64
#define MROWS 32

typedef __attribute__((ext_vector_type(8))) short v8s;
typedef __attribute__((ext_vector_type(4))) float v4f;

__device__ inline unsigned short f2bf(float f) {
  __hip_bfloat16 h = __float2bfloat16(f);   // hardware RNE convert
  return *reinterpret_cast<unsigned short*>(&h);
}

__device__ inline float gelu_f(float x) {
  float u = 0.7978845608028654f * (x + 0.044715f * x * x * x);
  float e = __expf(2.0f * u);
  float t = 1.0f - 2.0f / (e + 1.0f);   // tanh(u), inf-safe
  return 0.5f * x * (1.0f + t);
}

// ---------------- one-shot prep ----------------
// Packs (bf16 MFMA B-fragment layout, P[((nt*nKT+kt)*64+l)*8+j] = W[kt*32+(l>>4)*8+j][nt*16+(l&15)]):
//   Wcat (640x256 = [Wk; Wa; 0.1*Wr])  @ 0       (163840 shorts)
//   Wb0  (256x256)                     @ 163840
//   Wb1  (256x256)                     @ 229376
//   Ww   (256x1024)                    @ 294912
//   Wq   (256x1024)                    @ 557056
//   Wad  (256x64)                      @ 819200  (ends 835584)
struct PrepParams {
  const float *Wk, *Wa, *Wr, *Wb0, *Wb1, *Ww, *Wq, *Wad;
  const float *bk, *ba, *br;
  unsigned short* P;
  float* bcomb;
  int* cnt;
};

__global__ void prep_kern(PrepParams pp) {
  const int tid = threadIdx.x;
  if (blockIdx.x == 3264) {
    pp.bcomb[tid] = pp.bk[tid] + pp.ba[tid] + 0.1f * pp.br[tid];
    if (tid < 2) pp.cnt[tid] = 0;
    return;
  }
  long gid = (long)blockIdx.x * 256 + tid;
  int K, Nc; long base; int seg;
  if      (gid < 163840) { K = 640; Nc = 256;  base = 0;      seg = 0; }
  else if (gid < 229376) { K = 256; Nc = 256;  base = 163840; seg = 1; }
  else if (gid < 294912) { K = 256; Nc = 256;  base = 229376; seg = 2; }
  else if (gid < 557056) { K = 256; Nc = 1024; base = 294912; seg = 3; }
  else if (gid < 819200) { K = 256; Nc = 1024; base = 557056; seg = 4; }
  else                   { K = 256; Nc = 64;   base = 819200; seg = 5; }
  long idx = gid - base;
  int j = (int)(idx & 7);
  int l = (int)((idx >> 3) & 63);
  long t = idx >> 9;
  int nKT = K >> 5;
  int kt = (int)(t % nKT), nt = (int)(t / nKT);
  int k = kt * 32 + (l >> 4) * 8 + j;
  int n = nt * 16 + (l & 15);
  float v;
  if (seg == 0) {
    if (k < 128)      v = pp.Wk[(long)k * 256 + n];
    else if (k < 384) v = pp.Wa[(long)(k - 128) * 256 + n];
    else              v = 0.1f * pp.Wr[(long)(k - 384) * 256 + n];
  } else if (seg == 1) v = pp.Wb0[(long)k * Nc + n];
  else if (seg == 2)   v = pp.Wb1[(long)k * Nc + n];
  else if (seg == 3)   v = pp.Ww[(long)k * Nc + n];
  else if (seg == 4)   v = pp.Wq[(long)k * Nc + n];
  else                 v = pp.Wad[(long)k * Nc + n];
  pp.P[gid] = f2bf(v);
}

// ---------------- role partition (32-row tiles) ----------------
__global__ void compact_kern(const int* __restrict__ role, int* __restrict__ wIdx,
                             int* __restrict__ qIdx, int* __restrict__ cnt) {
  int r = blockIdx.x * 256 + threadIdx.x;
  int lane = threadIdx.x & 63;
  bool w = (role[r] == 0);
  unsigned long long mw = __ballot(w);
  unsigned long long below = (lane == 0) ? 0ull : (~0ull >> (64 - lane));
  int pw = __popcll(mw & below);
  int cw = __popcll(mw);
  int base = 0;
  if (lane == 0) base = atomicAdd(&cnt[0], cw);
  base = __shfl(base, 0);
  if (w) wIdx[base + pw] = r;
  unsigned long long mq = ~mw;
  int pq = __popcll(mq & below);
  int cq = 64 - cw;
  int baseq = 0;
  if (lane == 0) baseq = atomicAdd(&cnt[1], cq);
  baseq = __shfl(baseq, 0);
  if (!w) qIdx[baseq + pq] = r;
}

__global__ void finalize_kern(const int* __restrict__ cnt, int* __restrict__ wIdx,
                              int* __restrict__ qIdx, int* __restrict__ meta) {
  int cw = cnt[0], cq = cnt[1];
  int nwT = (cw + MROWS - 1) / MROWS, nqT = (cq + MROWS - 1) / MROWS;
  int tid = threadIdx.x;
  for (int i = cw + tid; i < nwT * MROWS; i += 64) wIdx[i] = -1;
  for (int i = cq + tid; i < nqT * MROWS; i += 64) qIdx[i] = -1;
  if (tid == 0) { meta[0] = nwT; meta[1] = nqT; }
}

// ---------------- shared GEMM helpers (32-row tiles) ----------------
// acc[m][nf] += tile(32 x K) @ fragment-packed W, wave n-tile base nt0
template<int NKT>
__device__ inline void gemm_acc(const unsigned short* __restrict__ Wp, int nt0,
                                const unsigned short (&tile)[MROWS][264], int lane,
                                v4f (&acc)[2][4]) {
  const int lr = lane & 15, lg = lane >> 4;
  #pragma unroll
  for (int kt = 0; kt < NKT; ++kt) {
    v8s b[4];
    #pragma unroll
    for (int nf = 0; nf < 4; ++nf)
      b[nf] = *reinterpret_cast<const v8s*>(Wp + (((long)(nt0 + nf) * NKT + kt) * 64 + lane) * 8);
    #pragma unroll
    for (int m = 0; m < 2; ++m) {
      v8s a = *reinterpret_cast<const v8s*>(&tile[m * 16 + lr][kt * 32 + lg * 8]);
      #pragma unroll
      for (int nf = 0; nf < 4; ++nf)
        acc[m][nf] = __builtin_amdgcn_mfma_f32_16x16x32_bf16(a, b[nf], acc[m][nf], 0, 0, 0);
    }
  }
}

__device__ inline void init_acc(v4f (&acc)[2][4], const float* __restrict__ bias,
                                int colbase, int lr) {
  #pragma unroll
  for (int nf = 0; nf < 4; ++nf) {
    float bv = bias[colbase + nf * 16 + lr];
    acc[0][nf] = (v4f){bv, bv, bv, bv};
    acc[1][nf] = (v4f){bv, bv, bv, bv};
  }
}

// GELU (opt) -> LayerNorm over 256 cols -> bf16 back into tile; opt f32 h out.
__device__ inline void ln_stage(v4f (&acc)[2][4], int wave, int lane,
                                const float* __restrict__ gamma, const float* __restrict__ beta,
                                bool do_gelu,
                                unsigned short (&tile)[MROWS][264], float (&stats)[2][4][MROWS],
                                float* __restrict__ h_out, long R0) {
  const int lr = lane & 15, lg = lane >> 4;
  if (do_gelu) {
    #pragma unroll
    for (int m = 0; m < 2; ++m)
      #pragma unroll
      for (int nf = 0; nf < 4; ++nf)
        #pragma unroll
        for (int r = 0; r < 4; ++r)
          acc[m][nf][r] = gelu_f(acc[m][nf][r]);
  }
  float s[2][4], q[2][4];
  #pragma unroll
  for (int m = 0; m < 2; ++m)
    #pragma unroll
    for (int r = 0; r < 4; ++r) {
      float t = 0.f, t2 = 0.f;
      #pragma unroll
      for (int nf = 0; nf < 4; ++nf) { float v = acc[m][nf][r]; t += v; t2 += v * v; }
      s[m][r] = t; q[m][r] = t2;
    }
  #pragma unroll
  for (int off = 1; off < 16; off <<= 1)
    #pragma unroll
    for (int m = 0; m < 2; ++m)
      #pragma unroll
      for (int r = 0; r < 4; ++r) {
        s[m][r] += __shfl_xor(s[m][r], off);
        q[m][r] += __shfl_xor(q[m][r], off);
      }
  if (lr == 0) {
    #pragma unroll
    for (int m = 0; m < 2; ++m)
      #pragma unroll
      for (int r = 0; r < 4; ++r) {
        int row = m * 16 + lg * 4 + r;
        stats[0][wave][row] = s[m][r];
        stats[1][wave][row] = q[m][r];
      }
  }
  __syncthreads();
  float gv[4], bv[4];
  #pragma unroll
  for (int nf = 0; nf < 4; ++nf) {
    int c = wave * 64 + nf * 16 + lr;
    gv[nf] = gamma[c]; bv[nf] = beta[c];
  }
  #pragma unroll
  for (int m = 0; m < 2; ++m)
    #pragma unroll
    for (int r = 0; r < 4; ++r) {
      int row = m * 16 + lg * 4 + r;
      float S = stats[0][0][row] + stats[0][1][row] + stats[0][2][row] + stats[0][3][row];
      float Q = stats[1][0][row] + stats[1][1][row] + stats[1][2][row] + stats[1][3][row];
      float mean = S * (1.0f / 256.0f);
      float var  = Q * (1.0f / 256.0f) - mean * mean;
      float rstd = rsqrtf(var + 1e-5f);
      #pragma unroll
      for (int nf = 0; nf < 4; ++nf) {
        int c = wave * 64 + nf * 16 + lr;
        float v = (acc[m][nf][r] - mean) * rstd * gv[nf] + bv[nf];
        tile[row][c] = f2bf(v);
        if (h_out) h_out[(R0 + row) * HDIM + c] = v;
      }
    }
  __syncthreads();
}

// ---------------- kernel A: backbone, natural row order ----------------
struct AParams {
  const float* key; const float* aux; const float* res;
  const unsigned short* pWcat; const unsigned short* pWb0; const unsigned short* pWb1;
  const unsigned short* pWad;
  const float* bcomb;
  const float* g_in; const float* b_in;
  const float* bb0; const float* g0; const float* be0;
  const float* bb1; const float* g1; const float* be1;
  const float* bad;
  float* out_h; float* out_aux;
};

__device__ inline const float* chunk_src(const AParams& p, long R0, int ck, int& stride) {
  if (ck < 2)      { stride = KD; return p.key + R0 * KD + ck * 64; }
  else if (ck < 6) { stride = DM; return p.aux + R0 * DM + (ck - 2) * 64; }
  else             { stride = DM; return p.res + R0 * DM + (ck - 6) * 64; }
}

__global__ __launch_bounds__(256, 5) void backbone_kern(AParams p) {
  __shared__ alignas(16) unsigned short tile[MROWS][264];
  __shared__ float stats[2][4][MROWS];

  const int tid = threadIdx.x;
  const int lane = tid & 63;
  const int wave = tid >> 6;
  const int lr = lane & 15;
  const int lg = lane >> 4;
  const long R0 = (long)blockIdx.x * MROWS;
  const int nt0 = wave * 4;

  // staging indices: 512 float4 per 32x64 chunk, 2 per thread
  const int r0 = tid >> 4,            c40 = tid & 15;
  const int r1 = (tid + 256) >> 4,    c41 = (tid + 256) & 15;

  v4f acc[2][4];
  init_acc(acc, p.bcomb, wave * 64, lr);

  // ---- stage 1: concat GEMM, K=640, 10 chunks of 64 cols, 2 LDS buffers ----
  int stride;
  const float* sp = chunk_src(p, R0, 0, stride);
  float4 s0 = *(const float4*)(sp + (long)r0 * stride + c40 * 4);
  float4 s1 = *(const float4*)(sp + (long)r1 * stride + c41 * 4);

  for (int ck = 0; ck < 10; ++ck) {
    // write staged chunk to LDS buffer ck&1
    {
      int cb = (ck & 1) * 64;
      unsigned long long pk0 = (unsigned long long)f2bf(s0.x)
                             | ((unsigned long long)f2bf(s0.y) << 16)
                             | ((unsigned long long)f2bf(s0.z) << 32)
                             | ((unsigned long long)f2bf(s0.w) << 48);
      unsigned long long pk1 = (unsigned long long)f2bf(s1.x)
                             | ((unsigned long long)f2bf(s1.y) << 16)
                             | ((unsigned long long)f2bf(s1.z) << 32)
                             | ((unsigned long long)f2bf(s1.w) << 48);
      *reinterpret_cast<unsigned long long*>(&tile[r0][cb + c40 * 4]) = pk0;
      *reinterpret_cast<unsigned long long*>(&tile[r1][cb + c41 * 4]) = pk1;
    }
    __syncthreads();
    // issue next chunk's loads (latency hides under this chunk's MFMAs)
    if (ck < 9) {
      sp = chunk_src(p, R0, ck + 1, stride);
      s0 = *(const float4*)(sp + (long)r0 * stride + c40 * 4);
      s1 = *(const float4*)(sp + (long)r1 * stride + c41 * 4);
    }
    // compute on buffer ck&1 (2 kt-tiles of the 20 total)
    #pragma unroll
    for (int kk = 0; kk < 2; ++kk) {
      int kt = ck * 2 + kk;
      v8s b[4];
      #pragma unroll
      for (int nf = 0; nf < 4; ++nf)
        b[nf] = *reinterpret_cast<const v8s*>(p.pWcat + (((long)(nt0 + nf) * 20 + kt) * 64 + lane) * 8);
      #pragma unroll
      for (int m = 0; m < 2; ++m) {
        v8s a = *reinterpret_cast<const v8s*>(&tile[m * 16 + lr][(ck & 1) * 64 + kk * 32 + lg * 8]);
        #pragma unroll
        for (int nf = 0; nf < 4; ++nf)
          acc[m][nf] = __builtin_amdgcn_mfma_f32_16x16x32_bf16(a, b[nf], acc[m][nf], 0, 0, 0);
      }
    }
    __syncthreads();
  }
  ln_stage(acc, wave, lane, p.g_in, p.b_in, false, tile, stats, nullptr, R0);

  // ---- backbone layer 0 ----
  init_acc(acc, p.bb0, wave * 64, lr);
  gemm_acc<8>(p.pWb0, nt0, tile, lane, acc);
  ln_stage(acc, wave, lane, p.g0, p.be0, true, tile, stats, nullptr, R0);

  // ---- backbone layer 1 (writes f32 h) ----
  init_acc(acc, p.bb1, wave * 64, lr);
  gemm_acc<8>(p.pWb1, nt0, tile, lane, acc);
  ln_stage(acc, wave, lane, p.g1, p.be1, true, tile, stats, p.out_h, R0);

  // ---- address head: wave w covers cols w*16..w*16+15 ----
  {
    v4f a4[2];
    float bv = p.bad[wave * 16 + lr];
    a4[0] = (v4f){bv, bv, bv, bv};
    a4[1] = (v4f){bv, bv, bv, bv};
    #pragma unroll
    for (int kt = 0; kt < 8; ++kt) {
      v8s b = *reinterpret_cast<const v8s*>(p.pWad + (((long)wave * 8 + kt) * 64 + lane) * 8);
      #pragma unroll
      for (int m = 0; m < 2; ++m) {
        v8s am = *reinterpret_cast<const v8s*>(&tile[m * 16 + lr][kt * 32 + lg * 8]);
        a4[m] = __builtin_amdgcn_mfma_f32_16x16x32_bf16(am, b, a4[m], 0, 0, 0);
      }
    }
    #pragma unroll
    for (int m = 0; m < 2; ++m)
      #pragma unroll
      for (int r = 0; r < 4; ++r) {
        int row = m * 16 + lg * 4 + r;
        p.out_aux[(R0 + row) * ADIM + wave * 16 + lr] = a4[m][r];
      }
  }
}

// ---------------- kernel B: role-dispatched head GEMM ----------------
struct HParams {
  const float* h;              // f32 h (from d_out)
  const unsigned short* pWw; const unsigned short* pWq;
  const float* bw; const float* bq;
  const int* wIdx; const int* qIdx; const int* meta;
  float* out_logits;
};

__global__ __launch_bounds__(256, 5) void head_kern(HParams p) {
  __shared__ alignas(16) unsigned short tile[MROWS][264];
  __shared__ int rows[MROWS];

  const int t = blockIdx.x;
  const int nwT = p.meta[0], nqT = p.meta[1];
  if (t >= nwT + nqT) return;
  const bool isW = (t < nwT);
  const int* list = isW ? (p.wIdx + (long)t * MROWS) : (p.qIdx + (long)(t - nwT) * MROWS);
  const unsigned short* Wp = isW ? p.pWw : p.pWq;
  const float* bias = isW ? p.bw : p.bq;

  const int tid = threadIdx.x;
  const int lane = tid & 63;
  const int wave = tid >> 6;
  const int lr = lane & 15;
  const int lg = lane >> 4;

  if (tid < MROWS) rows[tid] = list[tid];
  __syncthreads();

  // gather 32 x 256 f32 h rows -> bf16 tile (8 float4 per thread)
  #pragma unroll
  for (int i = 0; i < 8; ++i) {
    int idx = tid + i * 256;
    int r = idx >> 6;
    int c4 = idx & 63;
    int ridx = rows[r];
    unsigned long long pk = 0ull;
    if (ridx >= 0) {
      float4 v = *(reinterpret_cast<const float4*>(p.h + (long)ridx * HDIM) + c4);
      pk = (unsigned long long)f2bf(v.x)
         | ((unsigned long long)f2bf(v.y) << 16)
         | ((unsigned long long)f2bf(v.z) << 32)
         | ((unsigned long long)f2bf(v.w) << 48);
    }
    *reinterpret_cast<unsigned long long*>(&tile[r][c4 * 4]) = pk;
  }
  __syncthreads();

  // wave owns 256 output cols (16 n-tiles) in 4 chunks of 4
  for (int c = 0; c < 4; ++c) {
    int nt0 = wave * 16 + c * 4;
    v4f acc[2][4];
    init_acc(acc, bias, nt0 * 16, lr);
    gemm_acc<8>(Wp, nt0, tile, lane, acc);
    #pragma unroll
    for (int m = 0; m < 2; ++m)
      #pragma unroll
      for (int r = 0; r < 4; ++r) {
        int row = m * 16 + lg * 4 + r;
        int ridx = rows[row];
        if (ridx < 0) continue;
        #pragma unroll
        for (int nf = 0; nf < 4; ++nf) {
          int col = (nt0 + nf) * 16 + lr;
          p.out_logits[(long)ridx * NCOMP + col] = acc[m][nf][r];
        }
      }
  }
}

extern "C" void kernel_launch(void* const* d_in, const int* in_sizes, int n_in,
                              void* d_out, int out_size, void* d_ws, size_t ws_size,
                              hipStream_t stream) {
  const float* key  = (const float*)d_in[0];
  const float* aux  = (const float*)d_in[1];
  const float* res  = (const float*)d_in[2];
  const int*   role = (const int*)d_in[3];
  const float* Wk = (const float*)d_in[4];   const float* bk = (const float*)d_in[5];
  const float* Wa = (const float*)d_in[6];   const float* ba = (const float*)d_in[7];
  const float* Wr = (const float*)d_in[8];   const float* br = (const float*)d_in[9];
  const float* g_in = (const float*)d_in[10]; const float* b_in = (const float*)d_in[11];
  const float* Wb0 = (const float*)d_in[12]; const float* bb0 = (const float*)d_in[13];
  const float* g0 = (const float*)d_in[14];  const float* be0 = (const float*)d_in[15];
  const float* Wb1 = (const float*)d_in[16]; const float* bb1 = (const float*)d_in[17];
  const float* g1 = (const float*)d_in[18];  const float* be1 = (const float*)d_in[19];
  const float* Ww = (const float*)d_in[20];  const float* bw = (const float*)d_in[21];
  const float* Wq = (const float*)d_in[22];  const float* bq = (const float*)d_in[23];
  const float* Wad = (const float*)d_in[24]; const float* bad = (const float*)d_in[25];

  unsigned short* wsp = (unsigned short*)d_ws;
  unsigned short* pWcat = wsp + 0;
  unsigned short* pWb0  = wsp + 163840;
  unsigned short* pWb1  = wsp + 229376;
  unsigned short* pWw   = wsp + 294912;
  unsigned short* pWq   = wsp + 557056;
  unsigned short* pWad  = wsp + 819200;
  char* wsb = (char*)d_ws;
  float* bcomb = (float*)(wsb + 1671168);
  int* wIdx = (int*)(wsb + 1672192);          // 131136 ints
  int* qIdx = (int*)(wsb + 2196736);          // 131136 ints
  int* cnt  = (int*)(wsb + 2721280);          // 2 ints
  int* meta = (int*)(wsb + 2721288);          // 2 ints

  PrepParams pp;
  pp.Wk = Wk; pp.Wa = Wa; pp.Wr = Wr; pp.Wb0 = Wb0; pp.Wb1 = Wb1;
  pp.Ww = Ww; pp.Wq = Wq; pp.Wad = Wad;
  pp.bk = bk; pp.ba = ba; pp.br = br;
  pp.P = wsp; pp.bcomb = bcomb; pp.cnt = cnt;
  prep_kern<<<3265, 256, 0, stream>>>(pp);

  compact_kern<<<N_PKT / 256, 256, 0, stream>>>(role, wIdx, qIdx, cnt);
  finalize_kern<<<1, 64, 0, stream>>>(cnt, wIdx, qIdx, meta);

  float* out = (float*)d_out;
  float* out_logits = out;
  float* out_h = out + (size_t)N_PKT * NCOMP;
  float* out_aux = out + (size_t)N_PKT * (NCOMP + HDIM);

  AParams A;
  A.key = key; A.aux = aux; A.res = res;
  A.pWcat = pWcat; A.pWb0 = pWb0; A.pWb1 = pWb1; A.pWad = pWad;
  A.bcomb = bcomb;
  A.g_in = g_in; A.b_in = b_in;
  A.bb0 = bb0; A.g0 = g0; A.be0 = be0;
  A.bb1 = bb1; A.g1 = g1; A.be1 = be1;
  A.bad = bad;
  A.out_h = out_h; A.out_aux = out_aux;
  backbone_kern<<<N_PKT / MROWS, 256, 0, stream>>>(A);

  HParams B;
  B.h = out_h;
  B.pWw = pWw; B.pWq = pWq; B.bw = bw; B.bq = bq;
  B.wIdx = wIdx; B.qIdx = qIdx; B.meta = meta;
  B.out_logits = out_logits;
  head_kern<<<N_PKT / MROWS + 2, 256, 0, stream>>>(B);
}